// Round 18
// baseline (71.278 us; speedup 1.0000x reference)
//
#include <hip/hip_runtime.h>
#include <cmath>

#define BATCH 8
#define CIN   64
#define HH    128
#define WW    128
#define COUT  64
#define KKT   9            // K*K taps
#define NOFF  18           // 2*K*K offset channels
#define PIX   16           // pixels per row segment
#define NPX   32           // output pixels per block (2 rows x 16)
#define KTOT  576          // GEMM K (tap-major: k = kk*64+ci)
#define WROWS 6            // window rows: r0-2 .. r0+3
#define WCOLS 24           // window cols: wbase-4 .. wbase+19
#define NSAMP (NPX*KKT)    // 288
#define KH3   192          // per-pass s_vals row length (3 taps x 64 ci)

typedef __bf16 bf16x8 __attribute__((ext_vector_type(8)));
typedef float  f32x4  __attribute__((ext_vector_type(4)));
typedef float  f32x2  __attribute__((ext_vector_type(2)));
typedef unsigned int u32;
typedef u32    u32x4  __attribute__((ext_vector_type(4)));

// Pre-packed bf16 weights in exact MFMA B-fragment order, tap-major K.
__device__ __bf16 g_wb[18 * 4 * 4 * 16 * 8];      // dcn:    [kb][couttile4][lg][lr][e]
__device__ __bf16 g_wboff[18 * 2 * 4 * 16 * 8];   // offset: [kb][ntile2][lg][lr][e]

__global__ __launch_bounds__(256)
void prep_w(const float* __restrict__ w_dcn, const float* __restrict__ w_off) {
    const int idx = blockIdx.x * 256 + threadIdx.x;      // 55296 total
    if (idx < 18 * 4 * 4 * 16 * 8) {
        const int e  = idx & 7;
        const int lr = (idx >> 3) & 15;
        const int lg = (idx >> 7) & 3;
        const int w  = (idx >> 9) & 3;
        const int kb = idx >> 11;
        const int cout = w * 16 + lr;
        const int k  = kb * 32 + lg * 8 + e;
        const int kk = k >> 6, ci = k & 63;
        g_wb[idx] = (__bf16)w_dcn[cout * KTOT + ci * KKT + kk];
    } else {
        const int j  = idx - 18 * 4 * 4 * 16 * 8;
        const int e  = j & 7;
        const int lr = (j >> 3) & 15;
        const int lg = (j >> 7) & 3;
        const int nt = (j >> 9) & 1;
        const int kb = j >> 10;
        const int oc = nt * 16 + lr;
        const int k  = kb * 32 + lg * 8 + e;
        const int kk = k >> 6, ci = k & 63;
        g_wboff[j] = (oc < NOFF) ? (__bf16)w_off[oc * KTOT + ci * KKT + kk] : (__bf16)0.f;
    }
}

// exact bf16-pair -> f32x2 unpack (bit ops, no cvt)
static __device__ __forceinline__ f32x2 unpk(u32 v) {
    f32x2 r;
    r.x = __builtin_bit_cast(float, v << 16);
    r.y = __builtin_bit_cast(float, v & 0xffff0000u);
    return r;
}

// pack two floats into one u32 of 2x bf16 (RNE via (__bf16) cast)
static __device__ __forceinline__ u32 pkbf(float a, float b) {
    const u32 lo = (u32)__builtin_bit_cast(unsigned short, (__bf16)a);
    const u32 hi = (u32)__builtin_bit_cast(unsigned short, (__bf16)b);
    return lo | (hi << 16);
}

__global__ __launch_bounds__(256)
void deform_fused(const float* __restrict__ x,
                  const float* __restrict__ b_off,
                  float* __restrict__ out) {
    // x window [yr][xr][ci] bf16, XOR-swizzled: elem ^= (xr&7)<<3.
    // Reused at the end as the K-half reduce buffer (f32x4, stride 5).
    __shared__ __align__(16) __bf16 s_xw[WROWS * WCOLS * 64];   // 18432 B
    // Third-K A operand [p][k'], XOR-swizzled: col ^= (p&7)<<3
    __shared__ __align__(16) __bf16 s_vals[NPX * KH3];          // 12288 B
    __shared__ float s_off[NPX * NOFF];                         // 2304 B
    __shared__ int   s_meta[NSAMP];      // fast<<31 | rowidx<<16 | sw0<<8 | sw1
    __shared__ int   s_yx[NSAMP];        // (y0<<16)|(x0&0xffff)  (slow path only)
    __shared__ float s_bw[NSAMP][4];     // bilinear corner weights

    const int blk   = blockIdx.x;                  // 4096 blocks
    const int wtile = blk % (WW / PIX);
    const int r0    = ((blk / (WW / PIX)) % (HH / 2)) * 2;
    const int b     = blk / ((WW / PIX) * (HH / 2));
    const int wbase = wtile * PIX;
    const int tid   = threadIdx.x;
    const int wid   = tid >> 6;
    const int lane  = tid & 63;
    const int lr    = lane & 15;
    const int lg    = lane >> 4;

    const float* __restrict__ xb = x + (size_t)b * CIN * HH * WW;
    const bool interior = (r0 >= 2) & (r0 <= HH - 4) & (wtile >= 1) & (wtile <= (WW / PIX) - 2);

    // ---- Phase 1: stage 6-row x window, 2 channels/task, b32 LDS stores ----
    for (int t = tid; t < 6 * 32 * WROWS; t += 256) {   // 1152 tasks
        const int c   = t % 6;
        const int cp  = (t / 6) & 31;                    // channel pair
        const int yr  = t / 192;                         // 0..5
        const int ci0 = cp * 2;
        const int y   = r0 - 2 + yr;
        const int xs  = wbase - 4 + c * 4;
        f32x4 va = {0.f, 0.f, 0.f, 0.f};
        f32x4 vb = {0.f, 0.f, 0.f, 0.f};
        if (interior) {
            const float* __restrict__ rp = xb + (size_t)ci0 * (HH * WW) + y * WW + xs;
            va = *(const f32x4*)rp;                      // 16B-aligned (wbase%16==0)
            vb = *(const f32x4*)(rp + HH * WW);
        } else if (y >= 0 && y < HH) {
            const float* __restrict__ rp = xb + (size_t)ci0 * (HH * WW) + y * WW + xs;
            if (xs >= 0 && xs <= WW - 4) {
                va = *(const f32x4*)rp;
                vb = *(const f32x4*)(rp + HH * WW);
            } else {
                #pragma unroll
                for (int dx = 0; dx < 4; ++dx) {
                    if (xs + dx >= 0 && xs + dx < WW) {
                        va[dx] = rp[dx];
                        vb[dx] = rp[dx + HH * WW];
                    }
                }
            }
        }
        const int eb = ((yr * WCOLS + c * 4) << 6) + ci0;
        #pragma unroll
        for (int dx = 0; dx < 4; ++dx) {
            const int elem = (eb + (dx << 6)) ^ (((c * 4 + dx) & 7) << 3);
            *(u32*)&s_xw[elem] = pkbf(va[dx], vb[dx]);   // swizzle is octet-granular; pair stays intact
        }
    }
    __syncthreads();

    // ---- Phase 2: offset conv via MFMA (4 waves = 2 px-groups x 2 oc-tiles, full K) ----
    {
        const int pg = wid >> 1;
        const int nt = wid & 1;
        f32x4 acc = {0.f, 0.f, 0.f, 0.f};
        #pragma unroll
        for (int kb = 0; kb < 18; ++kb) {
            const int kbase = kb * 32 + lg * 8;
            const int kk    = kbase >> 6;
            const int ci0   = kbase & 63;
            const int yr    = pg + kk / 3 + 1;           // window row for y = r0+pg+ky-1
            const int xr    = lr + kk % 3 + 3;
            const int elem  = (((yr * WCOLS + xr) << 6) + ci0) ^ ((xr & 7) << 3);
            const bf16x8 a  = *(const bf16x8*)&s_xw[elem];
            const bf16x8 bb = *(const bf16x8*)&g_wboff[(((kb * 2 + nt) * 4 + lg) * 16 + lr) * 8];
            acc = __builtin_amdgcn_mfma_f32_16x16x32_bf16(a, bb, acc, 0, 0, 0);
        }
        const int oc = nt * 16 + lr;                     // C: col=lr->oc, row=lg*4+r->px-in-group
        if (oc < NOFF) {
            const float bias = b_off[oc];
            #pragma unroll
            for (int r = 0; r < 4; ++r)
                s_off[(pg * 16 + lg * 4 + r) * NOFF + oc] = acc[r] + bias;
        }
    }
    __syncthreads();

    // ---- Phase 3: coords + bilinear weights + precomputed fast-path meta ----
    for (int m = tid; m < NSAMP; m += 256) {
        const int p  = m / KKT;                          // 0..31
        const int kk = m - p * KKT;
        const int hp = r0 + (p >> 4);
        const int wo = wbase + (p & 15);
        const float py = (float)(hp - 1 + kk / 3) + s_off[p * NOFF + 2 * kk + 0];
        const float px = (float)(wo - 1 + kk % 3) + s_off[p * NOFF + 2 * kk + 1];
        const float fy = floorf(py), fx = floorf(px);
        const int y0 = (int)fy, x0 = (int)fx;
        const float dy = py - fy, dx = px - fx;
        const int yr = y0 - (r0 - 2);
        const int xr = x0 - (wbase - 4);
        const int fast = (yr >= 0) & (yr <= 4) & (xr >= 0) & (xr <= 22);
        const u32 rowidx = (u32)(yr * WCOLS + xr);       // 0..118 when fast
        s_meta[m] = fast ? (int)(0x80000000u | (rowidx << 16)
                                 | (((u32)(xr & 7) << 3) << 8)
                                 | ((u32)((xr + 1) & 7) << 3))
                         : 0;
        s_yx[m] = (y0 << 16) | (x0 & 0xffff);
        s_bw[m][0] = (1.f - dy) * (1.f - dx);
        s_bw[m][1] = (1.f - dy) * dx;
        s_bw[m][2] = dy * (1.f - dx);
        s_bw[m][3] = dy * dx;
    }
    __syncthreads();

    // ---- Bilinear task body (same math as r17; meta-driven addressing) ----
    auto run_task = [&](int m, int p, int kkl, int c8) {
        const int meta = s_meta[m];
        const f32x4 w = *(const f32x4*)&s_bw[m][0];
        bf16x8 o;
        if (meta < 0) {   // fast path
            const u32 um  = (u32)meta;
            const int r6  = (int)((um >> 16) & 0xffu) << 6;   // rowidx*64
            const int sw0 = (int)((um >> 8) & 0xffu);
            const int sw1 = (int)(um & 0xffu);
            const int a0  = r6 + (c8 ^ sw0);
            const int a1  = r6 + 64 + (c8 ^ sw1);
            const u32x4 u00 = *(const u32x4*)&s_xw[a0];
            const u32x4 u01 = *(const u32x4*)&s_xw[a1];
            const u32x4 u10 = *(const u32x4*)&s_xw[a0 + WCOLS * 64];
            const u32x4 u11 = *(const u32x4*)&s_xw[a1 + WCOLS * 64];
            #pragma unroll
            for (int u = 0; u < 4; ++u) {
                f32x2 a = unpk(u00[u]) * w[0];
                a += unpk(u01[u]) * w[1];
                a += unpk(u10[u]) * w[2];
                a += unpk(u11[u]) * w[3];
                o[2 * u + 0] = (__bf16)a.x;
                o[2 * u + 1] = (__bf16)a.y;
            }
        } else {
            const int yx = s_yx[m];
            const int y0 = yx >> 16;
            const int x0 = (int)(short)(yx & 0xffff);
            const int y1 = y0 + 1, x1 = x0 + 1;
            #pragma unroll
            for (int e = 0; e < 8; ++e) {
                const float* __restrict__ xc = xb + (size_t)(c8 + e) * (HH * WW);
                float v = 0.f;
                if (y0 >= 0 && y0 < HH) {
                    if (x0 >= 0 && x0 < WW) v += xc[y0 * WW + x0] * w[0];
                    if (x1 >= 0 && x1 < WW) v += xc[y0 * WW + x1] * w[1];
                }
                if (y1 >= 0 && y1 < HH) {
                    if (x0 >= 0 && x0 < WW) v += xc[y1 * WW + x0] * w[2];
                    if (x1 >= 0 && x1 < WW) v += xc[y1 * WW + x1] * w[3];
                }
                o[e] = (__bf16)v;
            }
        }
        const int ew = (kkl * 64 + c8) ^ ((p & 7) << 3);
        *(bf16x8*)&s_vals[p * KH3 + ew] = o;
    };

    // ---- Phase 5 wave roles: pg = px group (output row), kh = K-half of each pass.
    //      Each wave reads only its own 3 A-fragments per pass and computes all
    //      4 cout tiles -> A-reads 144 -> 36 per block. K-halves reduced at end.
    const int pg5 = wid >> 1;
    const int kh  = wid & 1;
    const int pix = pg5 * 16 + lr;

    f32x4 acc[4] = {{0.f,0.f,0.f,0.f}, {0.f,0.f,0.f,0.f},
                    {0.f,0.f,0.f,0.f}, {0.f,0.f,0.f,0.f}};

    // ---- Three K-passes: taps {0..2}, {3..5}, {6..8} ----
    #pragma unroll 1
    for (int pass = 0; pass < 3; ++pass) {
        // bilinear: 32 px x 3 taps x 8 octets = 768 tasks
        for (int t = tid; t < 768; t += 256) {
            const int s3 = t >> 3, c8 = (t & 7) << 3;
            const int p = s3 / 3, kkl = s3 - p * 3;
            run_task(p * KKT + pass * 3 + kkl, p, kkl, c8);
        }
        __syncthreads();
        // GEMM: this wave's 3 kb (j = kh*3 .. kh*3+2), 4 cout tiles each
        #pragma unroll
        for (int jj = 0; jj < 3; ++jj) {
            const int j  = kh * 3 + jj;
            const int kb = pass * 6 + j;
            const int ew = (j * 32 + lg * 8) ^ ((lr & 7) << 3);
            const bf16x8 a = *(const bf16x8*)&s_vals[pix * KH3 + ew];
            const __bf16* __restrict__ bp = g_wb + (size_t)kb * 2048 + lg * 128 + lr * 8;
            #pragma unroll
            for (int t4 = 0; t4 < 4; ++t4)
                acc[t4] = __builtin_amdgcn_mfma_f32_16x16x32_bf16(
                    a, *(const bf16x8*)(bp + t4 * 512), acc[t4], 0, 0, 0);
        }
        if (pass < 2) __syncthreads();
    }
    __syncthreads();   // all s_xw / s_vals reads done; reuse s_xw as reduce buffer

    // ---- K-half reduce through LDS (stride 5 f32x4 -> conflict-free; r15 pattern) ----
    f32x4* red = (f32x4*)s_xw;
    if (kh == 1) {
        const int base = (pg5 * 64 + lane) * 5;
        red[base + 0] = acc[0];
        red[base + 1] = acc[1];
        red[base + 2] = acc[2];
        red[base + 3] = acc[3];
    }
    __syncthreads();
    if (kh == 0) {
        const int base = (pg5 * 64 + lane) * 5;
        acc[0] += red[base + 0];
        acc[1] += red[base + 1];
        acc[2] += red[base + 2];
        acc[3] += red[base + 3];
        // D: col=lr -> cout within tile, row=lg*4+r -> x-position
        const size_t orow = ((size_t)b * COUT + lr) * HH + r0 + pg5;
        const size_t ocol = wbase + lg * 4;
        *(f32x4*)&out[(orow +  0 * (size_t)HH) * WW + ocol] = acc[0];   // cout = lr
        *(f32x4*)&out[(orow + 16 * (size_t)HH) * WW + ocol] = acc[1];   // cout = 16+lr
        *(f32x4*)&out[(orow + 32 * (size_t)HH) * WW + ocol] = acc[2];   // cout = 32+lr
        *(f32x4*)&out[(orow + 48 * (size_t)HH) * WW + ocol] = acc[3];   // cout = 48+lr
    }
}

extern "C" void kernel_launch(void* const* d_in, const int* in_sizes, int n_in,
                              void* d_out, int out_size, void* d_ws, size_t ws_size,
                              hipStream_t stream) {
    const float* x     = (const float*)d_in[0];
    const float* w_off = (const float*)d_in[1];
    const float* b_off = (const float*)d_in[2];
    const float* w_dcn = (const float*)d_in[3];
    float* out = (float*)d_out;

    prep_w<<<216, 256, 0, stream>>>(w_dcn, w_off);

    const int nblocks = BATCH * (HH / 2) * (WW / PIX);   // 4096
    deform_fused<<<nblocks, 256, 0, stream>>>(x, b_off, out);
}

// Round 19
// 64.695 us; speedup vs baseline: 1.1018x; 1.1018x over previous
//
#include <hip/hip_runtime.h>
#include <cmath>

#define BATCH 8
#define CIN   64
#define HH    128
#define WW    128
#define COUT  64
#define KKT   9            // K*K taps
#define NOFF  18           // 2*K*K offset channels
#define PIX   16           // pixels per row segment
#define NPX   32           // output pixels per block (2 rows x 16)
#define KTOT  576          // GEMM K (tap-major: k = kk*64+ci)
#define WROWS 6            // window rows: r0-2 .. r0+3
#define WCOLS 24           // window cols: wbase-4 .. wbase+19
#define NSAMP (NPX*KKT)    // 288
#define KH3   192          // per-pass s_vals row length (3 taps x 64 ci)

typedef __bf16 bf16x8 __attribute__((ext_vector_type(8)));
typedef float  f32x4  __attribute__((ext_vector_type(4)));
typedef float  f32x2  __attribute__((ext_vector_type(2)));
typedef unsigned int u32;
typedef u32    u32x4  __attribute__((ext_vector_type(4)));

// Pre-packed bf16 weights in exact MFMA B-fragment order, tap-major K.
__device__ __bf16 g_wb[18 * 4 * 4 * 16 * 8];      // dcn:    [kb][couttile4][lg][lr][e]
__device__ __bf16 g_wboff[18 * 2 * 4 * 16 * 8];   // offset: [kb][ntile2][lg][lr][e]

__global__ __launch_bounds__(256)
void prep_w(const float* __restrict__ w_dcn, const float* __restrict__ w_off) {
    const int idx = blockIdx.x * 256 + threadIdx.x;      // 55296 total
    if (idx < 18 * 4 * 4 * 16 * 8) {
        const int e  = idx & 7;
        const int lr = (idx >> 3) & 15;
        const int lg = (idx >> 7) & 3;
        const int w  = (idx >> 9) & 3;
        const int kb = idx >> 11;
        const int cout = w * 16 + lr;
        const int k  = kb * 32 + lg * 8 + e;
        const int kk = k >> 6, ci = k & 63;
        g_wb[idx] = (__bf16)w_dcn[cout * KTOT + ci * KKT + kk];
    } else {
        const int j  = idx - 18 * 4 * 4 * 16 * 8;
        const int e  = j & 7;
        const int lr = (j >> 3) & 15;
        const int lg = (j >> 7) & 3;
        const int nt = (j >> 9) & 1;
        const int kb = j >> 10;
        const int oc = nt * 16 + lr;
        const int k  = kb * 32 + lg * 8 + e;
        const int kk = k >> 6, ci = k & 63;
        g_wboff[j] = (oc < NOFF) ? (__bf16)w_off[oc * KTOT + ci * KKT + kk] : (__bf16)0.f;
    }
}

// exact bf16-pair -> f32x2 unpack (bit ops, no cvt)
static __device__ __forceinline__ f32x2 unpk(u32 v) {
    f32x2 r;
    r.x = __builtin_bit_cast(float, v << 16);
    r.y = __builtin_bit_cast(float, v & 0xffff0000u);
    return r;
}

// pack two floats into one u32 of 2x bf16 (RNE via (__bf16) cast)
static __device__ __forceinline__ u32 pkbf(float a, float b) {
    const u32 lo = (u32)__builtin_bit_cast(unsigned short, (__bf16)a);
    const u32 hi = (u32)__builtin_bit_cast(unsigned short, (__bf16)b);
    return lo | (hi << 16);
}

__global__ __launch_bounds__(256)
void deform_fused(const float* __restrict__ x,
                  const float* __restrict__ b_off,
                  float* __restrict__ out) {
    // x window [yr][xr][ci] bf16, XOR-swizzled: elem ^= (xr&7)<<3
    __shared__ __align__(16) __bf16 s_xw[WROWS * WCOLS * 64];   // 18432 B
    // Third-K A operand [p][k'], XOR-swizzled: col ^= (p&7)<<3
    __shared__ __align__(16) __bf16 s_vals[NPX * KH3];          // 12288 B
    __shared__ float s_off[NPX * NOFF];                         // 2304 B
    __shared__ int   s_meta[NSAMP];      // fast<<31 | rowidx<<16 | sw0<<8 | sw1
    __shared__ int   s_yx[NSAMP];        // (y0<<16)|(x0&0xffff)  (slow path only)
    __shared__ float s_bw[NSAMP][4];     // bilinear corner weights

    const int blk   = blockIdx.x;                  // 4096 blocks
    const int wtile = blk % (WW / PIX);
    const int r0    = ((blk / (WW / PIX)) % (HH / 2)) * 2;
    const int b     = blk / ((WW / PIX) * (HH / 2));
    const int wbase = wtile * PIX;
    const int tid   = threadIdx.x;
    const int wid   = tid >> 6;
    const int lane  = tid & 63;
    const int lr    = lane & 15;
    const int lg    = lane >> 4;

    const float* __restrict__ xb = x + (size_t)b * CIN * HH * WW;
    const bool interior = (r0 >= 2) & (r0 <= HH - 4) & (wtile >= 1) & (wtile <= (WW / PIX) - 2);

    // ---- Phase 1: stage 6-row x window, 2 channels/task, b32 LDS stores ----
    for (int t = tid; t < 6 * 32 * WROWS; t += 256) {   // 1152 tasks
        const int c   = t % 6;
        const int cp  = (t / 6) & 31;                    // channel pair
        const int yr  = t / 192;                         // 0..5
        const int ci0 = cp * 2;
        const int y   = r0 - 2 + yr;
        const int xs  = wbase - 4 + c * 4;
        f32x4 va = {0.f, 0.f, 0.f, 0.f};
        f32x4 vb = {0.f, 0.f, 0.f, 0.f};
        if (interior) {
            const float* __restrict__ rp = xb + (size_t)ci0 * (HH * WW) + y * WW + xs;
            va = *(const f32x4*)rp;                      // 16B-aligned (wbase%16==0)
            vb = *(const f32x4*)(rp + HH * WW);
        } else if (y >= 0 && y < HH) {
            const float* __restrict__ rp = xb + (size_t)ci0 * (HH * WW) + y * WW + xs;
            if (xs >= 0 && xs <= WW - 4) {
                va = *(const f32x4*)rp;
                vb = *(const f32x4*)(rp + HH * WW);
            } else {
                #pragma unroll
                for (int dx = 0; dx < 4; ++dx) {
                    if (xs + dx >= 0 && xs + dx < WW) {
                        va[dx] = rp[dx];
                        vb[dx] = rp[dx + HH * WW];
                    }
                }
            }
        }
        const int eb = ((yr * WCOLS + c * 4) << 6) + ci0;
        #pragma unroll
        for (int dx = 0; dx < 4; ++dx) {
            const int elem = (eb + (dx << 6)) ^ (((c * 4 + dx) & 7) << 3);
            *(u32*)&s_xw[elem] = pkbf(va[dx], vb[dx]);   // swizzle is octet-granular; pair stays intact
        }
    }
    __syncthreads();

    // ---- Phase 2: offset conv via MFMA (4 waves = 2 px-groups x 2 oc-tiles, full K) ----
    {
        const int pg = wid >> 1;
        const int nt = wid & 1;
        f32x4 acc = {0.f, 0.f, 0.f, 0.f};
        #pragma unroll
        for (int kb = 0; kb < 18; ++kb) {
            const int kbase = kb * 32 + lg * 8;
            const int kk    = kbase >> 6;
            const int ci0   = kbase & 63;
            const int yr    = pg + kk / 3 + 1;           // window row for y = r0+pg+ky-1
            const int xr    = lr + kk % 3 + 3;
            const int elem  = (((yr * WCOLS + xr) << 6) + ci0) ^ ((xr & 7) << 3);
            const bf16x8 a  = *(const bf16x8*)&s_xw[elem];
            const bf16x8 bb = *(const bf16x8*)&g_wboff[(((kb * 2 + nt) * 4 + lg) * 16 + lr) * 8];
            acc = __builtin_amdgcn_mfma_f32_16x16x32_bf16(a, bb, acc, 0, 0, 0);
        }
        const int oc = nt * 16 + lr;                     // C: col=lr->oc, row=lg*4+r->px-in-group
        if (oc < NOFF) {
            const float bias = b_off[oc];
            #pragma unroll
            for (int r = 0; r < 4; ++r)
                s_off[(pg * 16 + lg * 4 + r) * NOFF + oc] = acc[r] + bias;
        }
    }
    __syncthreads();

    // ---- Phase 3: coords + bilinear weights + precomputed fast-path meta ----
    for (int m = tid; m < NSAMP; m += 256) {
        const int p  = m / KKT;                          // 0..31
        const int kk = m - p * KKT;
        const int hp = r0 + (p >> 4);
        const int wo = wbase + (p & 15);
        const float py = (float)(hp - 1 + kk / 3) + s_off[p * NOFF + 2 * kk + 0];
        const float px = (float)(wo - 1 + kk % 3) + s_off[p * NOFF + 2 * kk + 1];
        const float fy = floorf(py), fx = floorf(px);
        const int y0 = (int)fy, x0 = (int)fx;
        const float dy = py - fy, dx = px - fx;
        const int yr = y0 - (r0 - 2);
        const int xr = x0 - (wbase - 4);
        const int fast = (yr >= 0) & (yr <= 4) & (xr >= 0) & (xr <= 22);
        const u32 rowidx = (u32)(yr * WCOLS + xr);       // 0..118 when fast
        s_meta[m] = fast ? (int)(0x80000000u | (rowidx << 16)
                                 | (((u32)(xr & 7) << 3) << 8)
                                 | ((u32)((xr + 1) & 7) << 3))
                         : 0;
        s_yx[m] = (y0 << 16) | (x0 & 0xffff);
        s_bw[m][0] = (1.f - dy) * (1.f - dx);
        s_bw[m][1] = (1.f - dy) * dx;
        s_bw[m][2] = dy * (1.f - dx);
        s_bw[m][3] = dy * dx;
    }
    __syncthreads();

    // ---- Bilinear task body (meta-driven addressing) ----
    auto run_task = [&](int m, int p, int kkl, int c8) {
        const int meta = s_meta[m];
        const f32x4 w = *(const f32x4*)&s_bw[m][0];
        bf16x8 o;
        if (meta < 0) {   // fast path
            const u32 um  = (u32)meta;
            const int r6  = (int)((um >> 16) & 0xffu) << 6;   // rowidx*64
            const int sw0 = (int)((um >> 8) & 0xffu);
            const int sw1 = (int)(um & 0xffu);
            const int a0  = r6 + (c8 ^ sw0);
            const int a1  = r6 + 64 + (c8 ^ sw1);
            const u32x4 u00 = *(const u32x4*)&s_xw[a0];
            const u32x4 u01 = *(const u32x4*)&s_xw[a1];
            const u32x4 u10 = *(const u32x4*)&s_xw[a0 + WCOLS * 64];
            const u32x4 u11 = *(const u32x4*)&s_xw[a1 + WCOLS * 64];
            #pragma unroll
            for (int u = 0; u < 4; ++u) {
                f32x2 a = unpk(u00[u]) * w[0];
                a += unpk(u01[u]) * w[1];
                a += unpk(u10[u]) * w[2];
                a += unpk(u11[u]) * w[3];
                o[2 * u + 0] = (__bf16)a.x;
                o[2 * u + 1] = (__bf16)a.y;
            }
        } else {
            const int yx = s_yx[m];
            const int y0 = yx >> 16;
            const int x0 = (int)(short)(yx & 0xffff);
            const int y1 = y0 + 1, x1 = x0 + 1;
            #pragma unroll
            for (int e = 0; e < 8; ++e) {
                const float* __restrict__ xc = xb + (size_t)(c8 + e) * (HH * WW);
                float v = 0.f;
                if (y0 >= 0 && y0 < HH) {
                    if (x0 >= 0 && x0 < WW) v += xc[y0 * WW + x0] * w[0];
                    if (x1 >= 0 && x1 < WW) v += xc[y0 * WW + x1] * w[1];
                }
                if (y1 >= 0 && y1 < HH) {
                    if (x0 >= 0 && x0 < WW) v += xc[y1 * WW + x0] * w[2];
                    if (x1 >= 0 && x1 < WW) v += xc[y1 * WW + x1] * w[3];
                }
                o[e] = (__bf16)v;
            }
        }
        const int ew = (kkl * 64 + c8) ^ ((p & 7) << 3);
        *(bf16x8*)&s_vals[p * KH3 + ew] = o;
    };

    f32x4 acc0 = {0.f, 0.f, 0.f, 0.f};
    f32x4 acc1 = {0.f, 0.f, 0.f, 0.f};
    const __bf16* __restrict__ bsrc = g_wb + (((size_t)wid * 4 + lg) * 16 + lr) * 8;

    // ---- Three K-passes: taps {0..2}, {3..5}, {6..8}; 6 kb x 2 px-groups each ----
    #pragma unroll 1
    for (int pass = 0; pass < 3; ++pass) {
        // bilinear: 32 px x 3 taps x 8 octets = 768 tasks
        for (int t = tid; t < 768; t += 256) {
            const int s3 = t >> 3, c8 = (t & 7) << 3;
            const int p = s3 / 3, kkl = s3 - p * 3;
            run_task(p * KKT + pass * 3 + kkl, p, kkl, c8);
        }
        __syncthreads();
        // GEMM: kb = pass*6 .. pass*6+5, both pixel groups share the B fragment
        #pragma unroll
        for (int j = 0; j < 6; ++j) {
            const int kb = pass * 6 + j;
            const int ew = (j * 32 + lg * 8) ^ ((lr & 7) << 3);
            const bf16x8 bf = *(const bf16x8*)(bsrc + (size_t)kb * 2048);
            const bf16x8 a0 = *(const bf16x8*)&s_vals[lr * KH3 + ew];
            const bf16x8 a1 = *(const bf16x8*)&s_vals[(16 + lr) * KH3 + ew];
            acc0 = __builtin_amdgcn_mfma_f32_16x16x32_bf16(a0, bf, acc0, 0, 0, 0);
            acc1 = __builtin_amdgcn_mfma_f32_16x16x32_bf16(a1, bf, acc1, 0, 0, 0);
        }
        if (pass < 2) __syncthreads();
    }

    const int cout = wid * 16 + lr;
    const size_t ob0 = (((size_t)b * COUT + cout) * HH + r0) * WW + wbase + lg * 4;
    *(f32x4*)&out[ob0]      = acc0;   // row r0
    *(f32x4*)&out[ob0 + WW] = acc1;   // row r0+1
}

extern "C" void kernel_launch(void* const* d_in, const int* in_sizes, int n_in,
                              void* d_out, int out_size, void* d_ws, size_t ws_size,
                              hipStream_t stream) {
    const float* x     = (const float*)d_in[0];
    const float* w_off = (const float*)d_in[1];
    const float* b_off = (const float*)d_in[2];
    const float* w_dcn = (const float*)d_in[3];
    float* out = (float*)d_out;

    prep_w<<<216, 256, 0, stream>>>(w_dcn, w_off);

    const int nblocks = BATCH * (HH / 2) * (WW / PIX);   // 4096
    deform_fused<<<nblocks, 256, 0, stream>>>(x, b_off, out);
}